// Round 1
// baseline (145.082 us; speedup 1.0000x reference)
//
#include <hip/hip_runtime.h>
#include <cstdint>
#include <cstddef>

// GraphAttentionLayer fused: B=8, N=2048, D=256
//  k_wh:   Wh = h @ W^T (bf16 MFMA, f32 acc), stores WhT[b][d][n] bf16 + s1,s2 f32
//  k_attn: out[i,:] = (sum_j exp(lrelu(s1_i+s2_j))*mask_ij * Wh[j,:]) / l_i
//          single pass, no max-subtraction (e bounded ~10), P built directly in
//          MFMA A-frag layout in registers; no barriers in j-loop.

#define NB 8
#define NN 2048
#define ND 256
#define ALPHA_F 0.2f

typedef __attribute__((ext_vector_type(8))) short short8;   // bf16x8 MFMA frag
typedef __attribute__((ext_vector_type(4))) float f32x4;    // MFMA acc frag
typedef __attribute__((ext_vector_type(4))) int   i32x4;

__device__ __forceinline__ unsigned short f2bf(float f) {
  union { float f; unsigned int u; } v; v.f = f;
  unsigned int r = v.u + 0x7FFFu + ((v.u >> 16) & 1u);   // RNE
  return (unsigned short)(r >> 16);
}

__device__ __forceinline__ short8 pack8(const float* v) {
  short8 r;
#pragma unroll
  for (int e = 0; e < 8; ++e) r[e] = (short)f2bf(v[e]);
  return r;
}

// ---------------- kernel 1: Wh = h @ W^T, + s1/s2, store WhT bf16 ----------
// grid: (B*N)/64 blocks, 256 thr (4 waves). Wave w owns cols [w*64, w*64+64).
__global__ __launch_bounds__(256) void k_wh(
    const float* __restrict__ h, const float* __restrict__ W,
    const float* __restrict__ a,
    unsigned short* __restrict__ WhT, float* __restrict__ s1g,
    float* __restrict__ s2g)
{
  __shared__ float sl1[64], sl2[64];
  const int tid  = threadIdx.x;
  const int wid  = tid >> 6;
  const int lane = tid & 63;
  const int l15  = lane & 15;
  const int c    = lane >> 4;
  const int r0   = blockIdx.x * 64;   // flattened (b,n) row base
  const int b    = r0 >> 11;
  const int n0   = r0 & 2047;

  if (tid < 64) { sl1[tid] = 0.f; sl2[tid] = 0.f; }

  f32x4 acc[4][4] = {};   // [mi][ni] : rows mi*16+l15-ish, cols wid*64+ni*16

  const float* hb   = h + (size_t)r0 * ND;
  const int ocol0   = wid * 64;

  for (int k0 = 0; k0 < ND; k0 += 32) {
    short8 afr[4], bfr[4];
#pragma unroll
    for (int mi = 0; mi < 4; ++mi) {
      const float* p = hb + (size_t)(mi * 16 + l15) * ND + k0 + c * 8;
      float t[8];
      *(f32x4*)t       = *(const f32x4*)p;
      *(f32x4*)(t + 4) = *(const f32x4*)(p + 4);
      afr[mi] = pack8(t);
    }
#pragma unroll
    for (int ni = 0; ni < 4; ++ni) {
      const int o = ocol0 + ni * 16 + l15;
      const float* p = W + (size_t)o * ND + k0 + c * 8;
      float t[8];
      *(f32x4*)t       = *(const f32x4*)p;
      *(f32x4*)(t + 4) = *(const f32x4*)(p + 4);
      bfr[ni] = pack8(t);
    }
#pragma unroll
    for (int mi = 0; mi < 4; ++mi)
#pragma unroll
      for (int ni = 0; ni < 4; ++ni)
        acc[mi][ni] = __builtin_amdgcn_mfma_f32_16x16x32_bf16(
            afr[mi], bfr[ni], acc[mi][ni], 0, 0, 0);
  }

  // s1/s2 partials from f32 accumulators (pre-rounding, for accuracy)
  float a1v[4], a2v[4];
#pragma unroll
  for (int ni = 0; ni < 4; ++ni) {
    const int o = ocol0 + ni * 16 + l15;
    a1v[ni] = a[o];
    a2v[ni] = a[ND + o];
  }
  float p1[4][4] = {}, p2[4][4] = {};
#pragma unroll
  for (int mi = 0; mi < 4; ++mi)
#pragma unroll
    for (int ni = 0; ni < 4; ++ni)
#pragma unroll
      for (int r = 0; r < 4; ++r) {
        p1[mi][r] += acc[mi][ni][r] * a1v[ni];
        p2[mi][r] += acc[mi][ni][r] * a2v[ni];
      }
#pragma unroll
  for (int m = 1; m <= 8; m <<= 1) {
#pragma unroll
    for (int mi = 0; mi < 4; ++mi)
#pragma unroll
      for (int r = 0; r < 4; ++r) {
        p1[mi][r] += __shfl_xor(p1[mi][r], m, 64);
        p2[mi][r] += __shfl_xor(p2[mi][r], m, 64);
      }
  }
  __syncthreads();   // LDS zero-init visible
  if (l15 == 0) {
#pragma unroll
    for (int mi = 0; mi < 4; ++mi)
#pragma unroll
      for (int r = 0; r < 4; ++r) {
        atomicAdd(&sl1[mi * 16 + c * 4 + r], p1[mi][r]);
        atomicAdd(&sl2[mi * 16 + c * 4 + r], p2[mi][r]);
      }
  }

  // WhT[b][o][n] store: frag regs r=0..3 are 4 consecutive n -> 8B dwordx2
#pragma unroll
  for (int mi = 0; mi < 4; ++mi)
#pragma unroll
    for (int ni = 0; ni < 4; ++ni) {
      const int o = ocol0 + ni * 16 + l15;
      const int n = n0 + mi * 16 + c * 4;
      unsigned short u4[4];
#pragma unroll
      for (int r = 0; r < 4; ++r) u4[r] = f2bf(acc[mi][ni][r]);
      *(uint2*)(WhT + ((size_t)b * ND + o) * NN + n) = *(uint2*)u4;
    }
  __syncthreads();
  if (tid < 64) { s1g[r0 + tid] = sl1[tid]; s2g[r0 + tid] = sl2[tid]; }
}

// ---------------- kernel 2: fused masked-exp attention GEMM ----------------
// grid: (N/32, B), 256 thr (4 waves). Wave w: rows [i0,i0+32), cols w*64..+64.
__global__ __launch_bounds__(256) void k_attn(
    const int* __restrict__ adj, const unsigned short* __restrict__ WhT,
    const float* __restrict__ s1g, const float* __restrict__ s2g,
    float* __restrict__ out)
{
  __shared__ float s2s[NN];
  __shared__ float lls[32];
  const int tid  = threadIdx.x;
  const int wid  = tid >> 6;
  const int lane = tid & 63;
  const int l15  = lane & 15;
  const int c    = lane >> 4;
  const int b    = blockIdx.y;
  const int i0   = blockIdx.x * 32;

  { // stage s2[b][:] into LDS
    const f32x4* src = (const f32x4*)(s2g + (size_t)b * NN);
    f32x4* dst = (f32x4*)s2s;
    for (int t = tid; t < NN / 4; t += 256) dst[t] = src[t];
  }
  float s1r[2];
#pragma unroll
  for (int mi = 0; mi < 2; ++mi)
    s1r[mi] = s1g[(size_t)b * NN + i0 + mi * 16 + l15];

  const int* ab            = adj + ((size_t)b * NN + i0) * NN;
  const unsigned short* wb = WhT + ((size_t)b * ND + wid * 64) * NN;

  f32x4 acc[2][4] = {};
  float lsum[2] = {0.f, 0.f};

  __syncthreads();

  for (int j0 = 0; j0 < NN; j0 += 32) {
    const int jj = j0 + c * 8;
    // adj: lane reads 8 ints of its row at its k-chunk (2x dwordx4)
    i32x4 ad[2][2];
#pragma unroll
    for (int mi = 0; mi < 2; ++mi) {
      const int* p = ab + (size_t)(mi * 16 + l15) * NN + jj;
      ad[mi][0] = *(const i32x4*)p;
      ad[mi][1] = *(const i32x4*)(p + 4);
    }
    // B-frags: 16B contiguous from WhT (L2-resident)
    short8 bfr[4];
#pragma unroll
    for (int ni = 0; ni < 4; ++ni)
      bfr[ni] = *(const short8*)(wb + (size_t)(ni * 16 + l15) * NN + jj);
    // s2 slice (broadcast within 16-lane groups)
    float s2v[8];
    *(f32x4*)s2v       = *(const f32x4*)(s2s + jj);
    *(f32x4*)(s2v + 4) = *(const f32x4*)(s2s + jj + 4);

    short8 afr[2];
#pragma unroll
    for (int mi = 0; mi < 2; ++mi) {
      float pv[8];
#pragma unroll
      for (int e = 0; e < 8; ++e) {
        float ev = s1r[mi] + s2v[e];
        ev = fmaxf(ev, ALPHA_F * ev);                  // leaky_relu
        const int av = (e < 4) ? ad[mi][0][e] : ad[mi][1][e - 4];
        pv[e] = (av > 0) ? __expf(ev) : 0.f;           // mask -> exact 0
      }
      float ls = 0.f;
#pragma unroll
      for (int e = 0; e < 8; ++e) ls += pv[e];
      lsum[mi] += ls;
      afr[mi] = pack8(pv);
    }
#pragma unroll
    for (int mi = 0; mi < 2; ++mi)
#pragma unroll
      for (int ni = 0; ni < 4; ++ni)
        acc[mi][ni] = __builtin_amdgcn_mfma_f32_16x16x32_bf16(
            afr[mi], bfr[ni], acc[mi][ni], 0, 0, 0);
  }

  // row-sum reduce across the 4 k-chunk lane groups
#pragma unroll
  for (int mi = 0; mi < 2; ++mi) {
    lsum[mi] += __shfl_xor(lsum[mi], 16, 64);
    lsum[mi] += __shfl_xor(lsum[mi], 32, 64);
  }
  if (wid == 0 && c == 0) { lls[l15] = lsum[0]; lls[16 + l15] = lsum[1]; }
  __syncthreads();

  float* ob = out + ((size_t)b * NN + i0) * ND + wid * 64;
#pragma unroll
  for (int mi = 0; mi < 2; ++mi)
#pragma unroll
    for (int r = 0; r < 4; ++r) {
      const int row = mi * 16 + c * 4 + r;
      const float linv = 1.0f / lls[row];
#pragma unroll
      for (int ni = 0; ni < 4; ++ni)
        ob[(size_t)row * ND + ni * 16 + l15] = acc[mi][ni][r] * linv;
    }
}

extern "C" void kernel_launch(void* const* d_in, const int* in_sizes, int n_in,
                              void* d_out, int out_size, void* d_ws, size_t ws_size,
                              hipStream_t stream) {
  const float* h   = (const float*)d_in[0];
  const int*   adj = (const int*)d_in[1];
  const float* W   = (const float*)d_in[2];
  const float* a   = (const float*)d_in[3];
  float* out = (float*)d_out;

  unsigned short* WhT = (unsigned short*)d_ws;                       // 8 MB bf16
  float* s1g = (float*)((char*)d_ws + (size_t)NB * ND * NN * 2);     // 64 KB
  float* s2g = s1g + (size_t)NB * NN;                                // 64 KB

  k_wh<<<dim3(NB * NN / 64), dim3(256), 0, stream>>>(h, W, a, WhT, s1g, s2g);
  k_attn<<<dim3(NN / 32, NB), dim3(256), 0, stream>>>(adj, WhT, s1g, s2g, out);
}

// Round 2
// 105.311 us; speedup vs baseline: 1.3777x; 1.3777x over previous
//
#include <hip/hip_runtime.h>
#include <cstdint>
#include <cstddef>

// GraphAttentionLayer fused: B=8, N=2048, D=256
//  k_wh:   Wh = h @ W^T (bf16 MFMA, f32 acc), stores WhT[b][d][n] bf16 + s1,s2 f32
//  k_attn: out[i,:] = (sum_j exp(lrelu(s1_i+s2_j))*mask_ij * Wh[j,:]) / l_i
//    v2: 8 waves/block, 2-way j-split, P built ONCE per j-group into LDS
//        (bf16, XOR-swizzled), cvt_pk packing, 1 barrier/chunk, LDS combine.

#define NB 8
#define NN 2048
#define ND 256
#define ALPHA_F 0.2f
#define JC 64          // j per chunk
#define NCH 16         // chunks per j-group (1024/64)

typedef __attribute__((ext_vector_type(8))) short short8;   // bf16x8 MFMA frag
typedef __attribute__((ext_vector_type(4))) float f32x4;    // MFMA acc frag
typedef __attribute__((ext_vector_type(4))) int   i32x4;

__device__ __forceinline__ unsigned short f2bf(float f) {
  union { float f; unsigned int u; } v; v.f = f;
  unsigned int r = v.u + 0x7FFFu + ((v.u >> 16) & 1u);   // RNE
  return (unsigned short)(r >> 16);
}

__device__ __forceinline__ short8 pack8(const float* v) {
  short8 r;
#pragma unroll
  for (int e = 0; e < 8; ++e) r[e] = (short)f2bf(v[e]);
  return r;
}

__device__ __forceinline__ unsigned int cvtpk(float lo, float hi) {
  unsigned int r;
  asm("v_cvt_pk_bf16_f32 %0, %1, %2" : "=v"(r) : "v"(lo), "v"(hi));
  return r;
}

// ---------------- kernel 1: Wh = h @ W^T, + s1/s2, store WhT bf16 ----------
// grid: (B*N)/64 blocks, 256 thr (4 waves). Wave w owns cols [w*64, w*64+64).
__global__ __launch_bounds__(256) void k_wh(
    const float* __restrict__ h, const float* __restrict__ W,
    const float* __restrict__ a,
    unsigned short* __restrict__ WhT, float* __restrict__ s1g,
    float* __restrict__ s2g)
{
  __shared__ float sl1[64], sl2[64];
  const int tid  = threadIdx.x;
  const int wid  = tid >> 6;
  const int lane = tid & 63;
  const int l15  = lane & 15;
  const int c    = lane >> 4;
  const int r0   = blockIdx.x * 64;   // flattened (b,n) row base
  const int b    = r0 >> 11;
  const int n0   = r0 & 2047;

  if (tid < 64) { sl1[tid] = 0.f; sl2[tid] = 0.f; }

  f32x4 acc[4][4] = {};

  const float* hb = h + (size_t)r0 * ND;
  const int ocol0 = wid * 64;

  for (int k0 = 0; k0 < ND; k0 += 32) {
    short8 afr[4], bfr[4];
#pragma unroll
    for (int mi = 0; mi < 4; ++mi) {
      const float* p = hb + (size_t)(mi * 16 + l15) * ND + k0 + c * 8;
      float t[8];
      *(f32x4*)t       = *(const f32x4*)p;
      *(f32x4*)(t + 4) = *(const f32x4*)(p + 4);
      afr[mi] = pack8(t);
    }
#pragma unroll
    for (int ni = 0; ni < 4; ++ni) {
      const int o = ocol0 + ni * 16 + l15;
      const float* p = W + (size_t)o * ND + k0 + c * 8;
      float t[8];
      *(f32x4*)t       = *(const f32x4*)p;
      *(f32x4*)(t + 4) = *(const f32x4*)(p + 4);
      bfr[ni] = pack8(t);
    }
#pragma unroll
    for (int mi = 0; mi < 4; ++mi)
#pragma unroll
      for (int ni = 0; ni < 4; ++ni)
        acc[mi][ni] = __builtin_amdgcn_mfma_f32_16x16x32_bf16(
            afr[mi], bfr[ni], acc[mi][ni], 0, 0, 0);
  }

  float a1v[4], a2v[4];
#pragma unroll
  for (int ni = 0; ni < 4; ++ni) {
    const int o = ocol0 + ni * 16 + l15;
    a1v[ni] = a[o];
    a2v[ni] = a[ND + o];
  }
  float p1[4][4] = {}, p2[4][4] = {};
#pragma unroll
  for (int mi = 0; mi < 4; ++mi)
#pragma unroll
    for (int ni = 0; ni < 4; ++ni)
#pragma unroll
      for (int r = 0; r < 4; ++r) {
        p1[mi][r] += acc[mi][ni][r] * a1v[ni];
        p2[mi][r] += acc[mi][ni][r] * a2v[ni];
      }
#pragma unroll
  for (int m = 1; m <= 8; m <<= 1) {
#pragma unroll
    for (int mi = 0; mi < 4; ++mi)
#pragma unroll
      for (int r = 0; r < 4; ++r) {
        p1[mi][r] += __shfl_xor(p1[mi][r], m, 64);
        p2[mi][r] += __shfl_xor(p2[mi][r], m, 64);
      }
  }
  __syncthreads();
  if (l15 == 0) {
#pragma unroll
    for (int mi = 0; mi < 4; ++mi)
#pragma unroll
      for (int r = 0; r < 4; ++r) {
        atomicAdd(&sl1[mi * 16 + c * 4 + r], p1[mi][r]);
        atomicAdd(&sl2[mi * 16 + c * 4 + r], p2[mi][r]);
      }
  }

#pragma unroll
  for (int mi = 0; mi < 4; ++mi)
#pragma unroll
    for (int ni = 0; ni < 4; ++ni) {
      const int o = ocol0 + ni * 16 + l15;
      const int n = n0 + mi * 16 + c * 4;
      unsigned short u4[4];
#pragma unroll
      for (int r = 0; r < 4; ++r) u4[r] = f2bf(acc[mi][ni][r]);
      *(uint2*)(WhT + ((size_t)b * ND + o) * NN + n) = *(uint2*)u4;
    }
  __syncthreads();
  if (tid < 64) { s1g[r0 + tid] = sl1[tid]; s2g[r0 + tid] = sl2[tid]; }
}

// ---------------- kernel 2: fused masked-exp attention GEMM (v2) -----------
// grid: 512 blocks 1D (b = bid&7 for XCD/L2 locality), 512 thr (8 waves).
// Wave wid: j-group = wid>>2 (half of j-range), col-group = wid&3 (64 cols).
// Per chunk of 64 j: 256 threads of the j-group build P[32][64] bf16 in LDS
// (swizzled), all 4 waves consume it as MFMA A-frags. Double-buffered,
// one barrier per chunk. acc combined across j-groups via LDS at the end.
__global__ __launch_bounds__(512, 4) void k_attn(
    const int* __restrict__ adj, const unsigned short* __restrict__ WhT,
    const float* __restrict__ s1g, const float* __restrict__ s2g,
    float* __restrict__ out)
{
  __shared__ __align__(16) char smem[32 * 1024 + 128];
  float*          s2s  = (float*)smem;                       // [0, 8K)
  unsigned short* pbuf = (unsigned short*)(smem + 8 * 1024); // [8K,24K): [jg][buf][32][64]
  float*          lsml = (float*)(smem + 32 * 1024);         // [32K, +128)
  float*          comb = (float*)smem;                       // [0,32K) alias after loop

  const int tid  = threadIdx.x;
  const int wid  = tid >> 6;
  const int lane = tid & 63;
  const int l15  = lane & 15;
  const int c    = lane >> 4;
  const int bid  = blockIdx.x;
  const int b    = bid & 7;           // batch -> XCD residue (L2 locality)
  const int i0   = (bid >> 3) * 32;

  // build-phase thread mapping
  const int lt     = tid & 255;
  const int jg     = tid >> 8;        // j-group 0/1 (== wid>>2)
  const int row    = lt & 31;
  const int jseg   = lt >> 5;         // 0..7, 8 j's each
  const int jgbase = jg * (NN / 2);
  const int gsw    = jseg ^ (row & 7);          // swizzled 16B granule
  const int wcol   = wid & 3;

  if (tid < 32) lsml[tid] = 0.f;
  { // stage s2[b][:] into LDS
    const f32x4* src = (const f32x4*)(s2g + (size_t)b * NN);
    f32x4* dst = (f32x4*)s2s;
    for (int t = tid; t < NN / 4; t += 512) dst[t] = src[t];
  }
  const float s1r = s1g[(size_t)b * NN + i0 + row];
  const int* abt = adj + ((size_t)(b * NN + i0 + row)) * NN + jgbase + jseg * 8;

  f32x4 acc[2][4] = {};
  float lacc = 0.f;

  __syncthreads();   // s2s ready

  const unsigned short* wb = WhT + ((size_t)b * ND + wcol * 64) * NN;
  unsigned short* pbW[2] = { pbuf + (jg * 2 + 0) * 2048, pbuf + (jg * 2 + 1) * 2048 };

#define BUILD(CH, BB)                                                        \
  {                                                                          \
    const int* ap = abt + (CH) * JC;                                         \
    i32x4 m0 = *(const i32x4*)ap;                                            \
    i32x4 m1 = *(const i32x4*)(ap + 4);                                      \
    const float* s2p = s2s + jgbase + (CH) * JC + jseg * 8;                  \
    f32x4 sa = *(const f32x4*)s2p;                                           \
    f32x4 sb = *(const f32x4*)(s2p + 4);                                     \
    float pv[8];                                                             \
    _Pragma("unroll")                                                        \
    for (int e = 0; e < 4; ++e) {                                            \
      float ev = s1r + sa[e];                                                \
      ev = fmaxf(ev, ALPHA_F * ev);                                          \
      pv[e] = (m0[e] > 0) ? __expf(ev) : 0.f;                                \
    }                                                                        \
    _Pragma("unroll")                                                        \
    for (int e = 0; e < 4; ++e) {                                            \
      float ev = s1r + sb[e];                                                \
      ev = fmaxf(ev, ALPHA_F * ev);                                          \
      pv[4 + e] = (m1[e] > 0) ? __expf(ev) : 0.f;                            \
    }                                                                        \
    lacc += ((pv[0] + pv[1]) + (pv[2] + pv[3])) +                            \
            ((pv[4] + pv[5]) + (pv[6] + pv[7]));                             \
    i32x4 pk;                                                                \
    pk[0] = (int)cvtpk(pv[0], pv[1]);                                        \
    pk[1] = (int)cvtpk(pv[2], pv[3]);                                        \
    pk[2] = (int)cvtpk(pv[4], pv[5]);                                        \
    pk[3] = (int)cvtpk(pv[6], pv[7]);                                        \
    *(i32x4*)(pbW[BB] + row * 64 + gsw * 8) = pk;                            \
  }

  BUILD(0, 0)
  __syncthreads();

  for (int ch = 0; ch < NCH; ++ch) {
    const int bb = ch & 1;
    const int jbase = jgbase + ch * JC;
    // MFMA phase: A-frags from LDS (swizzled), B-frags from L2-resident WhT
    const unsigned short* pbR = pbW[bb];
    short8 afr[2][2], bfr[2][4];
#pragma unroll
    for (int ks = 0; ks < 2; ++ks)
#pragma unroll
      for (int mi = 0; mi < 2; ++mi)
        afr[ks][mi] = *(const short8*)(pbR + (mi * 16 + l15) * 64 +
                                       (((ks * 4 + c) ^ (l15 & 7)) * 8));
#pragma unroll
    for (int ks = 0; ks < 2; ++ks)
#pragma unroll
      for (int ni = 0; ni < 4; ++ni)
        bfr[ks][ni] = *(const short8*)(wb + (size_t)(ni * 16 + l15) * NN +
                                       jbase + ks * 32 + c * 8);
    if (ch + 1 < NCH) BUILD(ch + 1, bb ^ 1)
#pragma unroll
    for (int ks = 0; ks < 2; ++ks)
#pragma unroll
      for (int mi = 0; mi < 2; ++mi)
#pragma unroll
        for (int ni = 0; ni < 4; ++ni)
          acc[mi][ni] = __builtin_amdgcn_mfma_f32_16x16x32_bf16(
              afr[ks][mi], bfr[ks][ni], acc[mi][ni], 0, 0, 0);
    __syncthreads();
  }

  // lsum: per-thread partial -> per-row total
  atomicAdd(&lsml[row], lacc);
  __syncthreads();

  // combine j-group partial accumulators via LDS
  if (jg == 1) {
#pragma unroll
    for (int mi = 0; mi < 2; ++mi)
#pragma unroll
      for (int r = 0; r < 4; ++r) {
        const int rr = mi * 16 + c * 4 + r;
#pragma unroll
        for (int ni = 0; ni < 4; ++ni)
          comb[rr * ND + wcol * 64 + ni * 16 + l15] = acc[mi][ni][r];
      }
  }
  __syncthreads();
  if (jg == 0) {
    float* ob = out + ((size_t)b * NN + i0) * ND + wcol * 64;
#pragma unroll
    for (int mi = 0; mi < 2; ++mi)
#pragma unroll
      for (int r = 0; r < 4; ++r) {
        const int rr = mi * 16 + c * 4 + r;
        const float linv = 1.0f / lsml[rr];
#pragma unroll
        for (int ni = 0; ni < 4; ++ni) {
          const float v = acc[mi][ni][r] + comb[rr * ND + wcol * 64 + ni * 16 + l15];
          ob[(size_t)rr * ND + ni * 16 + l15] = v * linv;
        }
      }
  }
#undef BUILD
}

extern "C" void kernel_launch(void* const* d_in, const int* in_sizes, int n_in,
                              void* d_out, int out_size, void* d_ws, size_t ws_size,
                              hipStream_t stream) {
  const float* h   = (const float*)d_in[0];
  const int*   adj = (const int*)d_in[1];
  const float* W   = (const float*)d_in[2];
  const float* a   = (const float*)d_in[3];
  float* out = (float*)d_out;

  unsigned short* WhT = (unsigned short*)d_ws;                       // 8 MB bf16
  float* s1g = (float*)((char*)d_ws + (size_t)NB * ND * NN * 2);     // 64 KB
  float* s2g = s1g + (size_t)NB * NN;                                // 64 KB

  k_wh<<<dim3(NB * NN / 64), dim3(256), 0, stream>>>(h, W, a, WhT, s1g, s2g);
  k_attn<<<dim3(NB * NN / 32), dim3(512), 0, stream>>>(adj, WhT, s1g, s2g, out);
}

// Round 3
// 103.336 us; speedup vs baseline: 1.4040x; 1.0191x over previous
//
#include <hip/hip_runtime.h>
#include <cstdint>
#include <cstddef>

// GraphAttentionLayer fused: B=8, N=2048, D=256
//  k_wh:   Wh = h @ W^T (bf16 MFMA, f32 acc), stores WhT[b][d][n] bf16 + s1,s2 f32
//  k_attn: out[i,:] = (sum_j exp(lrelu(s1_i+s2_j))*mask_ij * Wh[j,:]) / l_i
//    v3: v2 + 3-deep register prefetch of adj across barriers (the adj load
//        latency was fully exposed per chunk in v2); full unroll for static
//        parity indexing.

#define NB 8
#define NN 2048
#define ND 256
#define ALPHA_F 0.2f
#define JC 64          // j per chunk
#define NCH 16         // chunks per j-group (1024/64)

typedef __attribute__((ext_vector_type(8))) short short8;   // bf16x8 MFMA frag
typedef __attribute__((ext_vector_type(4))) float f32x4;    // MFMA acc frag
typedef __attribute__((ext_vector_type(4))) int   i32x4;

__device__ __forceinline__ unsigned short f2bf(float f) {
  union { float f; unsigned int u; } v; v.f = f;
  unsigned int r = v.u + 0x7FFFu + ((v.u >> 16) & 1u);   // RNE
  return (unsigned short)(r >> 16);
}

__device__ __forceinline__ short8 pack8(const float* v) {
  short8 r;
#pragma unroll
  for (int e = 0; e < 8; ++e) r[e] = (short)f2bf(v[e]);
  return r;
}

__device__ __forceinline__ unsigned int cvtpk(float lo, float hi) {
  unsigned int r;
  asm("v_cvt_pk_bf16_f32 %0, %1, %2" : "=v"(r) : "v"(lo), "v"(hi));
  return r;
}

// ---------------- kernel 1: Wh = h @ W^T, + s1/s2, store WhT bf16 ----------
__global__ __launch_bounds__(256) void k_wh(
    const float* __restrict__ h, const float* __restrict__ W,
    const float* __restrict__ a,
    unsigned short* __restrict__ WhT, float* __restrict__ s1g,
    float* __restrict__ s2g)
{
  __shared__ float sl1[64], sl2[64];
  const int tid  = threadIdx.x;
  const int wid  = tid >> 6;
  const int lane = tid & 63;
  const int l15  = lane & 15;
  const int c    = lane >> 4;
  const int r0   = blockIdx.x * 64;   // flattened (b,n) row base
  const int b    = r0 >> 11;
  const int n0   = r0 & 2047;

  if (tid < 64) { sl1[tid] = 0.f; sl2[tid] = 0.f; }

  f32x4 acc[4][4] = {};

  const float* hb = h + (size_t)r0 * ND;
  const int ocol0 = wid * 64;

  for (int k0 = 0; k0 < ND; k0 += 32) {
    short8 afr[4], bfr[4];
#pragma unroll
    for (int mi = 0; mi < 4; ++mi) {
      const float* p = hb + (size_t)(mi * 16 + l15) * ND + k0 + c * 8;
      float t[8];
      *(f32x4*)t       = *(const f32x4*)p;
      *(f32x4*)(t + 4) = *(const f32x4*)(p + 4);
      afr[mi] = pack8(t);
    }
#pragma unroll
    for (int ni = 0; ni < 4; ++ni) {
      const int o = ocol0 + ni * 16 + l15;
      const float* p = W + (size_t)o * ND + k0 + c * 8;
      float t[8];
      *(f32x4*)t       = *(const f32x4*)p;
      *(f32x4*)(t + 4) = *(const f32x4*)(p + 4);
      bfr[ni] = pack8(t);
    }
#pragma unroll
    for (int mi = 0; mi < 4; ++mi)
#pragma unroll
      for (int ni = 0; ni < 4; ++ni)
        acc[mi][ni] = __builtin_amdgcn_mfma_f32_16x16x32_bf16(
            afr[mi], bfr[ni], acc[mi][ni], 0, 0, 0);
  }

  float a1v[4], a2v[4];
#pragma unroll
  for (int ni = 0; ni < 4; ++ni) {
    const int o = ocol0 + ni * 16 + l15;
    a1v[ni] = a[o];
    a2v[ni] = a[ND + o];
  }
  float p1[4][4] = {}, p2[4][4] = {};
#pragma unroll
  for (int mi = 0; mi < 4; ++mi)
#pragma unroll
    for (int ni = 0; ni < 4; ++ni)
#pragma unroll
      for (int r = 0; r < 4; ++r) {
        p1[mi][r] += acc[mi][ni][r] * a1v[ni];
        p2[mi][r] += acc[mi][ni][r] * a2v[ni];
      }
#pragma unroll
  for (int m = 1; m <= 8; m <<= 1) {
#pragma unroll
    for (int mi = 0; mi < 4; ++mi)
#pragma unroll
      for (int r = 0; r < 4; ++r) {
        p1[mi][r] += __shfl_xor(p1[mi][r], m, 64);
        p2[mi][r] += __shfl_xor(p2[mi][r], m, 64);
      }
  }
  __syncthreads();
  if (l15 == 0) {
#pragma unroll
    for (int mi = 0; mi < 4; ++mi)
#pragma unroll
      for (int r = 0; r < 4; ++r) {
        atomicAdd(&sl1[mi * 16 + c * 4 + r], p1[mi][r]);
        atomicAdd(&sl2[mi * 16 + c * 4 + r], p2[mi][r]);
      }
  }

#pragma unroll
  for (int mi = 0; mi < 4; ++mi)
#pragma unroll
    for (int ni = 0; ni < 4; ++ni) {
      const int o = ocol0 + ni * 16 + l15;
      const int n = n0 + mi * 16 + c * 4;
      unsigned short u4[4];
#pragma unroll
      for (int r = 0; r < 4; ++r) u4[r] = f2bf(acc[mi][ni][r]);
      *(uint2*)(WhT + ((size_t)b * ND + o) * NN + n) = *(uint2*)u4;
    }
  __syncthreads();
  if (tid < 64) { s1g[r0 + tid] = sl1[tid]; s2g[r0 + tid] = sl2[tid]; }
}

// ---------------- kernel 2: fused masked-exp attention GEMM (v3) -----------
// grid: 512 blocks 1D (b = bid&7 for XCD/L2 locality), 512 thr (8 waves).
// Wave wid: j-group = wid>>2 (half of j-range), col-group = wid&3 (64 cols).
// Per chunk of 64 j: 256 threads of a j-group build P[32][64] bf16 in LDS
// (swizzled), the 4 waves consume it as MFMA A-frags. Double-buffered pbuf,
// one barrier per chunk. adj register-prefetched 3 chunks deep so its
// global-load latency is hidden across barriers.
__global__ __launch_bounds__(512, 4) void k_attn(
    const int* __restrict__ adj, const unsigned short* __restrict__ WhT,
    const float* __restrict__ s1g, const float* __restrict__ s2g,
    float* __restrict__ out)
{
  __shared__ __align__(16) char smem[32 * 1024 + 128];
  float*          s2s  = (float*)smem;                       // [0, 8K)
  unsigned short* pbuf = (unsigned short*)(smem + 8 * 1024); // [8K,24K): [jg][buf][32][64]
  float*          lsml = (float*)(smem + 32 * 1024);         // [32K, +128)
  float*          comb = (float*)smem;                       // [0,32K) alias after loop

  const int tid  = threadIdx.x;
  const int wid  = tid >> 6;
  const int lane = tid & 63;
  const int l15  = lane & 15;
  const int c    = lane >> 4;
  const int bid  = blockIdx.x;
  const int b    = bid & 7;           // batch -> XCD residue (L2 locality)
  const int i0   = (bid >> 3) * 32;

  // build-phase thread mapping
  const int lt     = tid & 255;
  const int jg     = tid >> 8;        // j-group 0/1 (== wid>>2)
  const int row    = lt & 31;
  const int jseg   = lt >> 5;         // 0..7, 8 j's each
  const int jgbase = jg * (NN / 2);
  const int gsw    = jseg ^ (row & 7);          // swizzled 16B granule
  const int wcol   = wid & 3;

  if (tid < 32) lsml[tid] = 0.f;
  { // stage s2[b][:] into LDS
    const f32x4* src = (const f32x4*)(s2g + (size_t)b * NN);
    f32x4* dst = (f32x4*)s2s;
    for (int t = tid; t < NN / 4; t += 512) dst[t] = src[t];
  }
  const float s1r = s1g[(size_t)b * NN + i0 + row];
  const int* abt = adj + ((size_t)(b * NN + i0 + row)) * NN + jgbase + jseg * 8;

  f32x4 acc[2][4] = {};
  float lacc = 0.f;

  const unsigned short* wb = WhT + ((size_t)b * ND + wcol * 64) * NN;
  unsigned short* pbW[2] = { pbuf + (jg * 2 + 0) * 2048, pbuf + (jg * 2 + 1) * 2048 };

  i32x4 adm[2][2];   // adj prefetch regs, [parity][halves of 8 ints]

#define LOADADJ(CH, P)                                                       \
  { const int* ap = abt + (CH) * JC;                                         \
    adm[P][0] = *(const i32x4*)ap;                                           \
    adm[P][1] = *(const i32x4*)(ap + 4); }

#define BUILDC(CH, BB, P)                                                    \
  {                                                                          \
    const float* s2p = s2s + jgbase + (CH) * JC + jseg * 8;                  \
    f32x4 sa = *(const f32x4*)s2p;                                           \
    f32x4 sb = *(const f32x4*)(s2p + 4);                                     \
    float pv[8];                                                             \
    _Pragma("unroll")                                                        \
    for (int e = 0; e < 4; ++e) {                                            \
      float ev = s1r + sa[e];                                                \
      ev = fmaxf(ev, ALPHA_F * ev);                                          \
      pv[e] = (adm[P][0][e] > 0) ? __expf(ev) : 0.f;                         \
    }                                                                        \
    _Pragma("unroll")                                                        \
    for (int e = 0; e < 4; ++e) {                                            \
      float ev = s1r + sb[e];                                                \
      ev = fmaxf(ev, ALPHA_F * ev);                                          \
      pv[4 + e] = (adm[P][1][e] > 0) ? __expf(ev) : 0.f;                     \
    }                                                                        \
    lacc += ((pv[0] + pv[1]) + (pv[2] + pv[3])) +                            \
            ((pv[4] + pv[5]) + (pv[6] + pv[7]));                             \
    i32x4 pk;                                                                \
    pk[0] = (int)cvtpk(pv[0], pv[1]);                                        \
    pk[1] = (int)cvtpk(pv[2], pv[3]);                                        \
    pk[2] = (int)cvtpk(pv[4], pv[5]);                                        \
    pk[3] = (int)cvtpk(pv[6], pv[7]);                                        \
    *(i32x4*)(pbW[BB] + row * 64 + gsw * 8) = pk;                            \
  }

  __syncthreads();   // s2s ready (also covers lsml init)

  // prologue: adj for chunks 0,1 -> parities 0,1; build chunk 0; refill p0
  LOADADJ(0, 0)
  LOADADJ(1, 1)
  BUILDC(0, 0, 0)
  LOADADJ(2, 0)
  __syncthreads();

#pragma unroll
  for (int ch = 0; ch < NCH; ++ch) {
    const int bb = ch & 1;
    const int jbase = jgbase + ch * JC;
    const unsigned short* pbR = pbW[bb];
    short8 afr[2][2], bfr[2][4];
#pragma unroll
    for (int ks = 0; ks < 2; ++ks)
#pragma unroll
      for (int mi = 0; mi < 2; ++mi)
        afr[ks][mi] = *(const short8*)(pbR + (mi * 16 + l15) * 64 +
                                       (((ks * 4 + c) ^ (l15 & 7)) * 8));
#pragma unroll
    for (int ks = 0; ks < 2; ++ks)
#pragma unroll
      for (int ni = 0; ni < 4; ++ni)
        bfr[ks][ni] = *(const short8*)(wb + (size_t)(ni * 16 + l15) * NN +
                                       jbase + ks * 32 + c * 8);
    if (ch + 1 < NCH) {
      BUILDC(ch + 1, (ch + 1) & 1, (ch + 1) & 1)
      if (ch + 3 < NCH) LOADADJ(ch + 3, (ch + 3) & 1)
    }
#pragma unroll
    for (int ks = 0; ks < 2; ++ks)
#pragma unroll
      for (int mi = 0; mi < 2; ++mi)
#pragma unroll
        for (int ni = 0; ni < 4; ++ni)
          acc[mi][ni] = __builtin_amdgcn_mfma_f32_16x16x32_bf16(
              afr[ks][mi], bfr[ks][ni], acc[mi][ni], 0, 0, 0);
    __syncthreads();
  }

  // lsum: per-thread partial -> per-row total
  atomicAdd(&lsml[row], lacc);
  __syncthreads();

  // combine j-group partial accumulators via LDS
  if (jg == 1) {
#pragma unroll
    for (int mi = 0; mi < 2; ++mi)
#pragma unroll
      for (int r = 0; r < 4; ++r) {
        const int rr = mi * 16 + c * 4 + r;
#pragma unroll
        for (int ni = 0; ni < 4; ++ni)
          comb[rr * ND + wcol * 64 + ni * 16 + l15] = acc[mi][ni][r];
      }
  }
  __syncthreads();
  if (jg == 0) {
    float* ob = out + ((size_t)b * NN + i0) * ND + wcol * 64;
#pragma unroll
    for (int mi = 0; mi < 2; ++mi)
#pragma unroll
      for (int r = 0; r < 4; ++r) {
        const int rr = mi * 16 + c * 4 + r;
        const float linv = 1.0f / lsml[rr];
#pragma unroll
        for (int ni = 0; ni < 4; ++ni) {
          const float v = acc[mi][ni][r] + comb[rr * ND + wcol * 64 + ni * 16 + l15];
          ob[(size_t)rr * ND + ni * 16 + l15] = v * linv;
        }
      }
  }
#undef BUILDC
#undef LOADADJ
}

extern "C" void kernel_launch(void* const* d_in, const int* in_sizes, int n_in,
                              void* d_out, int out_size, void* d_ws, size_t ws_size,
                              hipStream_t stream) {
  const float* h   = (const float*)d_in[0];
  const int*   adj = (const int*)d_in[1];
  const float* W   = (const float*)d_in[2];
  const float* a   = (const float*)d_in[3];
  float* out = (float*)d_out;

  unsigned short* WhT = (unsigned short*)d_ws;                       // 8 MB bf16
  float* s1g = (float*)((char*)d_ws + (size_t)NB * ND * NN * 2);     // 64 KB
  float* s2g = s1g + (size_t)NB * NN;                                // 64 KB

  k_wh<<<dim3(NB * NN / 64), dim3(256), 0, stream>>>(h, W, a, WhT, s1g, s2g);
  k_attn<<<dim3(NB * NN / 32), dim3(512), 0, stream>>>(adj, WhT, s1g, s2g, out);
}

// Round 5
// 103.146 us; speedup vs baseline: 1.4066x; 1.0018x over previous
//
#include <hip/hip_runtime.h>
#include <cstdint>
#include <cstddef>

// GraphAttentionLayer fused: B=8, N=2048, D=256
//  k_wh:   Wh = h @ W^T (bf16 MFMA, f32 acc), stores WhT[b][d][n] bf16 + s1,s2 f32
//  k_attn: out[i,:] = (sum_j exp(lrelu(s1_i+s2_j))*mask_ij * Wh[j,:]) / l_i
//    v5: = v4 (raw s_barrier + lgkmcnt(0) only, counted vmcnt across barriers)
//      with the v4 register-ordering bug fixed: BUILDC(ch+1) must consume
//      adm[(ch+1)&1] BEFORE LOADADJ(ch+3) overwrites the same parity register
//      (v4 hoisted the load above the build -> wrong adjacency used).

#define NB 8
#define NN 2048
#define ND 256
#define ALPHA_F 0.2f
#define JC 64          // j per chunk
#define NCH 16         // chunks per j-group (1024/64)

typedef __attribute__((ext_vector_type(8))) short short8;   // bf16x8 MFMA frag
typedef __attribute__((ext_vector_type(4))) float f32x4;    // MFMA acc frag
typedef __attribute__((ext_vector_type(4))) int   i32x4;

__device__ __forceinline__ unsigned short f2bf(float f) {
  union { float f; unsigned int u; } v; v.f = f;
  unsigned int r = v.u + 0x7FFFu + ((v.u >> 16) & 1u);   // RNE
  return (unsigned short)(r >> 16);
}

__device__ __forceinline__ short8 pack8(const float* v) {
  short8 r;
#pragma unroll
  for (int e = 0; e < 8; ++e) r[e] = (short)f2bf(v[e]);
  return r;
}

__device__ __forceinline__ unsigned int cvtpk(float lo, float hi) {
  unsigned int r;
  asm("v_cvt_pk_bf16_f32 %0, %1, %2" : "=v"(r) : "v"(lo), "v"(hi));
  return r;
}

// ---------------- kernel 1: Wh = h @ W^T, + s1/s2, store WhT bf16 ----------
__global__ __launch_bounds__(256) void k_wh(
    const float* __restrict__ h, const float* __restrict__ W,
    const float* __restrict__ a,
    unsigned short* __restrict__ WhT, float* __restrict__ s1g,
    float* __restrict__ s2g)
{
  __shared__ float sl1[64], sl2[64];
  const int tid  = threadIdx.x;
  const int wid  = tid >> 6;
  const int lane = tid & 63;
  const int l15  = lane & 15;
  const int c    = lane >> 4;
  const int r0   = blockIdx.x * 64;   // flattened (b,n) row base
  const int b    = r0 >> 11;
  const int n0   = r0 & 2047;

  if (tid < 64) { sl1[tid] = 0.f; sl2[tid] = 0.f; }

  f32x4 acc[4][4] = {};

  const float* hb = h + (size_t)r0 * ND;
  const int ocol0 = wid * 64;

  for (int k0 = 0; k0 < ND; k0 += 32) {
    short8 afr[4], bfr[4];
#pragma unroll
    for (int mi = 0; mi < 4; ++mi) {
      const float* p = hb + (size_t)(mi * 16 + l15) * ND + k0 + c * 8;
      float t[8];
      *(f32x4*)t       = *(const f32x4*)p;
      *(f32x4*)(t + 4) = *(const f32x4*)(p + 4);
      afr[mi] = pack8(t);
    }
#pragma unroll
    for (int ni = 0; ni < 4; ++ni) {
      const int o = ocol0 + ni * 16 + l15;
      const float* p = W + (size_t)o * ND + k0 + c * 8;
      float t[8];
      *(f32x4*)t       = *(const f32x4*)p;
      *(f32x4*)(t + 4) = *(const f32x4*)(p + 4);
      bfr[ni] = pack8(t);
    }
#pragma unroll
    for (int mi = 0; mi < 4; ++mi)
#pragma unroll
      for (int ni = 0; ni < 4; ++ni)
        acc[mi][ni] = __builtin_amdgcn_mfma_f32_16x16x32_bf16(
            afr[mi], bfr[ni], acc[mi][ni], 0, 0, 0);
  }

  float a1v[4], a2v[4];
#pragma unroll
  for (int ni = 0; ni < 4; ++ni) {
    const int o = ocol0 + ni * 16 + l15;
    a1v[ni] = a[o];
    a2v[ni] = a[ND + o];
  }
  float p1[4][4] = {}, p2[4][4] = {};
#pragma unroll
  for (int mi = 0; mi < 4; ++mi)
#pragma unroll
    for (int ni = 0; ni < 4; ++ni)
#pragma unroll
      for (int r = 0; r < 4; ++r) {
        p1[mi][r] += acc[mi][ni][r] * a1v[ni];
        p2[mi][r] += acc[mi][ni][r] * a2v[ni];
      }
#pragma unroll
  for (int m = 1; m <= 8; m <<= 1) {
#pragma unroll
    for (int mi = 0; mi < 4; ++mi)
#pragma unroll
      for (int r = 0; r < 4; ++r) {
        p1[mi][r] += __shfl_xor(p1[mi][r], m, 64);
        p2[mi][r] += __shfl_xor(p2[mi][r], m, 64);
      }
  }
  __syncthreads();
  if (l15 == 0) {
#pragma unroll
    for (int mi = 0; mi < 4; ++mi)
#pragma unroll
      for (int r = 0; r < 4; ++r) {
        atomicAdd(&sl1[mi * 16 + c * 4 + r], p1[mi][r]);
        atomicAdd(&sl2[mi * 16 + c * 4 + r], p2[mi][r]);
      }
  }

#pragma unroll
  for (int mi = 0; mi < 4; ++mi)
#pragma unroll
    for (int ni = 0; ni < 4; ++ni) {
      const int o = ocol0 + ni * 16 + l15;
      const int n = n0 + mi * 16 + c * 4;
      unsigned short u4[4];
#pragma unroll
      for (int r = 0; r < 4; ++r) u4[r] = f2bf(acc[mi][ni][r]);
      *(uint2*)(WhT + ((size_t)b * ND + o) * NN + n) = *(uint2*)u4;
    }
  __syncthreads();
  if (tid < 64) { s1g[r0 + tid] = sl1[tid]; s2g[r0 + tid] = sl2[tid]; }
}

// ---------------- kernel 2: fused masked-exp attention GEMM (v5) -----------
// grid: 512 blocks 1D (b = bid&7 for XCD/L2 locality), 512 thr (8 waves).
// Wave wid: j-group = wid>>2 (half of j-range), col-group = wid&3 (64 cols).
// Per chunk of 64 j: 256 threads of a j-group build P[32][64] bf16 in LDS
// (swizzled), the 4 waves consume it as MFMA A-frags. Double-buffered pbuf,
// ONE RAW barrier per chunk (lgkmcnt(0) only — vmcnt stays counted so the
// adj register prefetch keeps the memory queue full across barriers).
__global__ __launch_bounds__(512, 4) void k_attn(
    const int* __restrict__ adj, const unsigned short* __restrict__ WhT,
    const float* __restrict__ s1g, const float* __restrict__ s2g,
    float* __restrict__ out)
{
  __shared__ __align__(16) char smem[32 * 1024 + 128];
  float*          s2s  = (float*)smem;                       // [0, 8K)
  unsigned short* pbuf = (unsigned short*)(smem + 8 * 1024); // [8K,24K): [jg][buf][32][64]
  float*          lsml = (float*)(smem + 32 * 1024);         // [32K, +128)
  float*          comb = (float*)smem;                       // [0,32K) alias after loop

  const int tid  = threadIdx.x;
  const int wid  = tid >> 6;
  const int lane = tid & 63;
  const int l15  = lane & 15;
  const int c    = lane >> 4;
  const int bid  = blockIdx.x;
  const int b    = bid & 7;           // batch -> XCD residue (L2 locality)
  const int i0   = (bid >> 3) * 32;

  // build-phase thread mapping
  const int lt     = tid & 255;
  const int jg     = tid >> 8;        // j-group 0/1 (== wid>>2)
  const int row    = lt & 31;
  const int jseg   = lt >> 5;         // 0..7, 8 j's each
  const int jgbase = jg * (NN / 2);
  const int gsw    = jseg ^ (row & 7);          // swizzled 16B granule
  const int wcol   = wid & 3;

  if (tid < 32) lsml[tid] = 0.f;
  { // stage s2[b][:] into LDS
    const f32x4* src = (const f32x4*)(s2g + (size_t)b * NN);
    f32x4* dst = (f32x4*)s2s;
    for (int t = tid; t < NN / 4; t += 512) dst[t] = src[t];
  }
  const float s1r = s1g[(size_t)b * NN + i0 + row];
  const int* abt = adj + ((size_t)(b * NN + i0 + row)) * NN + jgbase + jseg * 8;

  f32x4 acc[2][4] = {};
  float lacc = 0.f;

  const unsigned short* wb = WhT + ((size_t)b * ND + wcol * 64) * NN;
  unsigned short* pbW[2] = { pbuf + (jg * 2 + 0) * 2048, pbuf + (jg * 2 + 1) * 2048 };

  i32x4 adm[2][2];   // adj prefetch regs, [parity][halves of 8 ints]

#define LOADADJ(CH, P)                                                       \
  { const int* ap = abt + (CH) * JC;                                         \
    adm[P][0] = *(const i32x4*)ap;                                           \
    adm[P][1] = *(const i32x4*)(ap + 4); }

#define BUILDC(CH, BB, P)                                                    \
  {                                                                          \
    const float* s2p = s2s + jgbase + (CH) * JC + jseg * 8;                  \
    f32x4 sa = *(const f32x4*)s2p;                                           \
    f32x4 sb = *(const f32x4*)(s2p + 4);                                     \
    float pv[8];                                                             \
    _Pragma("unroll")                                                        \
    for (int e = 0; e < 4; ++e) {                                            \
      float ev = s1r + sa[e];                                                \
      ev = fmaxf(ev, ALPHA_F * ev);                                          \
      pv[e] = (adm[P][0][e] > 0) ? __expf(ev) : 0.f;                         \
    }                                                                        \
    _Pragma("unroll")                                                        \
    for (int e = 0; e < 4; ++e) {                                            \
      float ev = s1r + sb[e];                                                \
      ev = fmaxf(ev, ALPHA_F * ev);                                          \
      pv[4 + e] = (adm[P][1][e] > 0) ? __expf(ev) : 0.f;                     \
    }                                                                        \
    lacc += ((pv[0] + pv[1]) + (pv[2] + pv[3])) +                            \
            ((pv[4] + pv[5]) + (pv[6] + pv[7]));                             \
    i32x4 pk;                                                                \
    pk[0] = (int)cvtpk(pv[0], pv[1]);                                        \
    pk[1] = (int)cvtpk(pv[2], pv[3]);                                        \
    pk[2] = (int)cvtpk(pv[4], pv[5]);                                        \
    pk[3] = (int)cvtpk(pv[6], pv[7]);                                        \
    *(i32x4*)(pbW[BB] + row * 64 + gsw * 8) = pk;                            \
  }

  // raw barrier: drain LDS ops only; global loads stay in flight (T4)
#define CHUNK_BARRIER()                                                      \
  { asm volatile("s_waitcnt lgkmcnt(0)" ::: "memory");                       \
    __builtin_amdgcn_s_barrier(); }

  __syncthreads();   // s2s + lsml ready (full drain once is fine here)

  // prologue: adj for chunks 0,1; build chunk 0; refill parity 0 with chunk 2
  LOADADJ(0, 0)
  LOADADJ(1, 1)
  BUILDC(0, 0, 0)
  LOADADJ(2, 0)
  CHUNK_BARRIER()

#pragma unroll
  for (int ch = 0; ch < NCH; ++ch) {
    const int bb = ch & 1;
    const int jbase = jgbase + ch * JC;
    const unsigned short* pbR = pbW[bb];
    short8 afr[2][2], bfr[2][4];
#pragma unroll
    for (int ks = 0; ks < 2; ++ks)
#pragma unroll
      for (int mi = 0; mi < 2; ++mi)
        afr[ks][mi] = *(const short8*)(pbR + (mi * 16 + l15) * 64 +
                                       (((ks * 4 + c) ^ (l15 & 7)) * 8));
#pragma unroll
    for (int ks = 0; ks < 2; ++ks)
#pragma unroll
      for (int ni = 0; ni < 4; ++ni)
        bfr[ks][ni] = *(const short8*)(wb + (size_t)(ni * 16 + l15) * NN +
                                       jbase + ks * 32 + c * 8);
    // consume-then-refill: BUILDC(ch+1) must read adm[(ch+1)&1] BEFORE
    // LOADADJ(ch+3) overwrites the same parity register.
    if (ch + 1 < NCH) {
      BUILDC(ch + 1, (ch + 1) & 1, (ch + 1) & 1)
      if (ch + 3 < NCH) LOADADJ(ch + 3, (ch + 3) & 1)
    }
#pragma unroll
    for (int ks = 0; ks < 2; ++ks)
#pragma unroll
      for (int mi = 0; mi < 2; ++mi)
#pragma unroll
        for (int ni = 0; ni < 4; ++ni)
          acc[mi][ni] = __builtin_amdgcn_mfma_f32_16x16x32_bf16(
              afr[ks][mi], bfr[ks][ni], acc[mi][ni], 0, 0, 0);
    CHUNK_BARRIER()
  }

  // lsum: per-thread partial -> per-row total
  atomicAdd(&lsml[row], lacc);
  __syncthreads();

  // combine j-group partial accumulators via LDS
  if (jg == 1) {
#pragma unroll
    for (int mi = 0; mi < 2; ++mi)
#pragma unroll
      for (int r = 0; r < 4; ++r) {
        const int rr = mi * 16 + c * 4 + r;
#pragma unroll
        for (int ni = 0; ni < 4; ++ni)
          comb[rr * ND + wcol * 64 + ni * 16 + l15] = acc[mi][ni][r];
      }
  }
  __syncthreads();
  if (jg == 0) {
    float* ob = out + ((size_t)b * NN + i0) * ND + wcol * 64;
#pragma unroll
    for (int mi = 0; mi < 2; ++mi)
#pragma unroll
      for (int r = 0; r < 4; ++r) {
        const int rr = mi * 16 + c * 4 + r;
        const float linv = 1.0f / lsml[rr];
#pragma unroll
        for (int ni = 0; ni < 4; ++ni) {
          const float v = acc[mi][ni][r] + comb[rr * ND + wcol * 64 + ni * 16 + l15];
          ob[(size_t)rr * ND + ni * 16 + l15] = v * linv;
        }
      }
  }
#undef BUILDC
#undef LOADADJ
#undef CHUNK_BARRIER
}

extern "C" void kernel_launch(void* const* d_in, const int* in_sizes, int n_in,
                              void* d_out, int out_size, void* d_ws, size_t ws_size,
                              hipStream_t stream) {
  const float* h   = (const float*)d_in[0];
  const int*   adj = (const int*)d_in[1];
  const float* W   = (const float*)d_in[2];
  const float* a   = (const float*)d_in[3];
  float* out = (float*)d_out;

  unsigned short* WhT = (unsigned short*)d_ws;                       // 8 MB bf16
  float* s1g = (float*)((char*)d_ws + (size_t)NB * ND * NN * 2);     // 64 KB
  float* s2g = s1g + (size_t)NB * NN;                                // 64 KB

  k_wh<<<dim3(NB * NN / 64), dim3(256), 0, stream>>>(h, W, a, WhT, s1g, s2g);
  k_attn<<<dim3(NB * NN / 32), dim3(512), 0, stream>>>(adj, WhT, s1g, s2g, out);
}